// Round 2
// baseline (1777.499 us; speedup 1.0000x reference)
//
#include <hip/hip_runtime.h>
#include <hip/hip_bf16.h>
#include <math.h>

// TemporalAttention: T=512, N=1024, D=256
//   e = score_w . tanh(H @ fc_w^T + fc_b)       (bf16 MFMA GEMM, B staged in LDS)
//   coefficients A_t,B_t via wave-parallel online-softmax prefix scan (fused)
//   C[t] = A_t*C[t-1] + B_t*H[t]                (streaming FMA scan, 2x8 reg banks)

#define T_DIM 512
#define N_DIM 1024
#define D_DIM 256

typedef short v8s __attribute__((ext_vector_type(8)));   // 8 bf16 (4 VGPRs)
typedef float v4f __attribute__((ext_vector_type(4)));   // 4 fp32 acc

__device__ __forceinline__ unsigned pk_bf16(float a, float b) {
    // RNE fp32->bf16, packed pair (b in high 16)
    unsigned ua = __builtin_bit_cast(unsigned, a);
    unsigned ub = __builtin_bit_cast(unsigned, b);
    ua = ua + 0x7fffu + ((ua >> 16) & 1u);
    ub = ub + 0x7fffu + ((ub >> 16) & 1u);
    return (ua >> 16) | (ub & 0xffff0000u);
}

__device__ __forceinline__ float fast_tanh(float x) {
    // tanh(x) = 1 - 2/(exp(2x)+1); handles +-inf limits correctly
    float e = __expf(2.0f * x);
    return 1.0f - 2.0f / (e + 1.0f);
}

// ---------------------------------------------------------------------------
// Kernel 1: e[t*N+n] = score_w . tanh(H_row @ fc_w^T + fc_b)
// B (fc_w, bf16) in LDS, fragment slot = ks*1024 + jt*64 + lane so the wave's
// ds_read_b128 is lane-contiguous (conflict-free). Waves fully independent
// (no barriers in main loop). jt-pair outer / ks inner keeps only 2 live
// accumulators; fc_b/score_w come from a small LDS table -> no spills.
// Explicit next-tile raw-A prefetch hides HBM latency.
// ---------------------------------------------------------------------------
#define SCORE_BLOCKS 256
#define SCORE_WAVES  (SCORE_BLOCKS * 8)

__global__ __launch_bounds__(512, 2) void k_score(
    const float* __restrict__ H, const float* __restrict__ fc_w,
    const float* __restrict__ fc_b, const float* __restrict__ score_w,
    float* __restrict__ e_out)
{
    __shared__ uint4 Bs[8192];               // 128 KB: slot = ks*1024 + jt*64 + lane
    __shared__ float fcb_s[256], scw_s[256]; // 2 KB

    const int tid  = threadIdx.x;            // 0..511
    const int l    = tid & 63;
    const int l15  = l & 15;
    const int quad = l >> 4;

    // --- stage fc_w -> LDS as bf16; LDS writes tid-contiguous (conflict-free) ---
#pragma unroll
    for (int i = 0; i < 16; ++i) {
        const int slot = i * 512 + tid;       // 0..8191
        const int sl15 = slot & 15;
        const int squad = (slot >> 4) & 3;
        const int sjt  = (slot >> 6) & 15;
        const int sks  = slot >> 10;
        const float* src = fc_w + (sjt * 16 + sl15) * D_DIM + sks * 32 + squad * 8;
        float4 b0 = ((const float4*)src)[0];
        float4 b1 = ((const float4*)src)[1];
        uint4 u;
        u.x = pk_bf16(b0.x, b0.y); u.y = pk_bf16(b0.z, b0.w);
        u.z = pk_bf16(b1.x, b1.y); u.w = pk_bf16(b1.z, b1.w);
        Bs[slot] = u;
    }
    if (tid < 256) { fcb_s[tid] = fc_b[tid]; scw_s[tid] = score_w[tid]; }
    __syncthreads();   // Bs ready; read-only afterwards -> no more barriers

    const v8s* Bv = (const v8s*)Bs;
    const int wid = tid >> 6;
    const int n_tiles = (T_DIM * N_DIM) / 16;      // 32768

    int mt = blockIdx.x * 8 + wid;                 // 16 tiles per wave exactly
    if (mt >= n_tiles) return;

    // prefetch first tile's raw A (16 x float4 = 64 VGPRs)
    float4 raw[16];
    {
        const float* hrow = H + (size_t)(mt * 16 + l15) * D_DIM + quad * 8;
#pragma unroll
        for (int ks = 0; ks < 8; ++ks) {
            raw[2 * ks]     = ((const float4*)(hrow + ks * 32))[0];
            raw[2 * ks + 1] = ((const float4*)(hrow + ks * 32))[1];
        }
    }

    while (true) {
        // pack current A fragments
        v8s af[8];
#pragma unroll
        for (int ks = 0; ks < 8; ++ks) {
            union { v8s v; unsigned u[4]; } f;
            f.u[0] = pk_bf16(raw[2 * ks].x,     raw[2 * ks].y);
            f.u[1] = pk_bf16(raw[2 * ks].z,     raw[2 * ks].w);
            f.u[2] = pk_bf16(raw[2 * ks + 1].x, raw[2 * ks + 1].y);
            f.u[3] = pk_bf16(raw[2 * ks + 1].z, raw[2 * ks + 1].w);
            af[ks] = f.v;
        }

        // issue next tile's raw loads (overlap with MFMA below)
        const int mt_next = mt + SCORE_WAVES;
        if (mt_next < n_tiles) {
            const float* hrow = H + (size_t)(mt_next * 16 + l15) * D_DIM + quad * 8;
#pragma unroll
            for (int ks = 0; ks < 8; ++ks) {
                raw[2 * ks]     = ((const float4*)(hrow + ks * 32))[0];
                raw[2 * ks + 1] = ((const float4*)(hrow + ks * 32))[1];
            }
        }

        // MFMA + fused epilogue, 2 j-tiles at a time (only 8 acc VGPRs live)
        float er[4] = {0.f, 0.f, 0.f, 0.f};
#pragma unroll
        for (int jp = 0; jp < 8; ++jp) {
            const v4f vz = {0.f, 0.f, 0.f, 0.f};
            v4f a0 = vz, a1 = vz;
#pragma unroll
            for (int ks = 0; ks < 8; ++ks) {
                a0 = __builtin_amdgcn_mfma_f32_16x16x32_bf16(
                    af[ks], Bv[ks * 1024 + (2 * jp) * 64 + l], a0, 0, 0, 0);
                a1 = __builtin_amdgcn_mfma_f32_16x16x32_bf16(
                    af[ks], Bv[ks * 1024 + (2 * jp + 1) * 64 + l], a1, 0, 0, 0);
            }
            const float fb0 = fcb_s[(2 * jp) * 16 + l15];
            const float sw0 = scw_s[(2 * jp) * 16 + l15];
            const float fb1 = fcb_s[(2 * jp + 1) * 16 + l15];
            const float sw1 = scw_s[(2 * jp + 1) * 16 + l15];
#pragma unroll
            for (int r = 0; r < 4; ++r) {
                er[r] += fast_tanh(a0[r] + fb0) * sw0
                       + fast_tanh(a1[r] + fb1) * sw1;
            }
        }

        // reduce over the 16 j-lanes (xor masks < 16 stay within quad group)
#pragma unroll
        for (int msk = 1; msk < 16; msk <<= 1) {
#pragma unroll
            for (int r = 0; r < 4; ++r)
                er[r] += __shfl_xor(er[r], msk, 64);
        }
        if (l15 == 0) {
#pragma unroll
            for (int r = 0; r < 4; ++r)
                e_out[mt * 16 + quad * 4 + r] = er[r];
        }

        if (mt_next >= n_tiles) break;
        mt = mt_next;
    }
}

// ---------------------------------------------------------------------------
// Kernel 2: per-n column: (a) wave 0 computes coefficients A_t,B_t via a
// wave-parallel online-softmax prefix scan into LDS; (b) all 256 threads
// stream C[t,n,:] = A_t*C[t-1,n,:] + B_t*H[t,n,:] using two named 8-deep
// register banks (16 loads in flight, x16 unrolled, branch-free inner body),
// nontemporal H loads / C stores.
// ---------------------------------------------------------------------------
__global__ __launch_bounds__(256) void k_apply(
    const float* __restrict__ H, const float* __restrict__ e,
    float* __restrict__ C)
{
    __shared__ float2 coef[T_DIM];   // 4 KB

    const int n   = blockIdx.x;
    const int tid = threadIdx.x;

    if (tid < 64) {
        // lane handles t = tid*8 .. tid*8+7
        float ev[8];
#pragma unroll
        for (int i = 0; i < 8; ++i)
            ev[i] = e[(tid * 8 + i) * N_DIM + n];

        // lane-local inclusive (m,s) fold
        float m = -INFINITY, s = 0.f;
#pragma unroll
        for (int i = 0; i < 8; ++i) {
            float mn = fmaxf(m, ev[i]);
            s = s * __expf(m - mn) + __expf(ev[i] - mn);
            m = mn;
        }
        // wave inclusive scan (associative combine of (m,s))
#pragma unroll
        for (int off = 1; off < 64; off <<= 1) {
            float mo = __shfl_up(m, off, 64);
            float so = __shfl_up(s, off, 64);
            if (tid >= off) {
                float mn = fmaxf(mo, m);
                s = s * __expf(m - mn) + so * __expf(mo - mn);
                m = mn;
            }
        }
        // exclusive prefix for this lane
        float pm = __shfl_up(m, 1, 64);
        float ps = __shfl_up(s, 1, 64);
        if (tid == 0) { pm = -INFINITY; ps = 0.f; }

        // replay the 8 steps from the carry-in, emitting A_t, B_t
        float mm = pm, ss = ps;
#pragma unroll
        for (int i = 0; i < 8; ++i) {
            float et    = ev[i];
            float mn    = fmaxf(mm, et);
            float alpha = __expf(mm - mn);
            float p     = __expf(et - mn);
            float sn    = ss * alpha + p;
            float rs    = 1.0f / sn;
            coef[tid * 8 + i] = make_float2(alpha * ss * rs, p * rs);
            mm = mn; ss = sn;
        }
    }
    __syncthreads();

    // phase 2: stream. 256 threads = one fp32 lane per d.
    const size_t base = (size_t)n * D_DIM + tid;
    const float* Hp = H + base;
    float*       Cp = C + base;
    const size_t st = (size_t)N_DIM * D_DIM;

    float ha[8], hb[8];
#pragma unroll
    for (int k = 0; k < 8; ++k)
        ha[k] = __builtin_nontemporal_load(&Hp[(size_t)k * st]);
#pragma unroll
    for (int k = 0; k < 8; ++k)
        hb[k] = __builtin_nontemporal_load(&Hp[(size_t)(8 + k) * st]);

    float num = 0.f;
    for (int g2 = 0; g2 < 32; ++g2) {         // 32 iterations x 16 t each
        const int t0 = g2 * 16;

        // consume bank A (t0 .. t0+7)
#pragma unroll
        for (int k = 0; k < 8; ++k) {
            float2 ab = coef[t0 + k];
            num = fmaf(num, ab.x, ab.y * ha[k]);
            __builtin_nontemporal_store(num, &Cp[(size_t)(t0 + k) * st]);
        }
        // refill bank A with group g2+2 (t0+16 ..)
        if (g2 < 31) {
#pragma unroll
            for (int k = 0; k < 8; ++k)
                ha[k] = __builtin_nontemporal_load(&Hp[(size_t)(t0 + 16 + k) * st]);
        }
        // consume bank B (t0+8 .. t0+15)
#pragma unroll
        for (int k = 0; k < 8; ++k) {
            float2 ab = coef[t0 + 8 + k];
            num = fmaf(num, ab.x, ab.y * hb[k]);
            __builtin_nontemporal_store(num, &Cp[(size_t)(t0 + 8 + k) * st]);
        }
        // refill bank B with group g2+3 (t0+24 ..)
        if (g2 < 31) {
#pragma unroll
            for (int k = 0; k < 8; ++k)
                hb[k] = __builtin_nontemporal_load(&Hp[(size_t)(t0 + 24 + k) * st]);
        }
    }
}

// ---------------------------------------------------------------------------
extern "C" void kernel_launch(void* const* d_in, const int* in_sizes, int n_in,
                              void* d_out, int out_size, void* d_ws, size_t ws_size,
                              hipStream_t stream) {
    const float* H       = (const float*)d_in[0];
    const float* fc_w    = (const float*)d_in[1];
    const float* fc_b    = (const float*)d_in[2];
    const float* score_w = (const float*)d_in[3];
    float* C = (float*)d_out;

    float* e = (float*)d_ws;   // 2 MB

    k_score<<<dim3(SCORE_BLOCKS), dim3(512), 0, stream>>>(H, fc_w, fc_b, score_w, e);
    k_apply<<<dim3(N_DIM), dim3(256), 0, stream>>>(H, e, C);
}